// Round 5
// baseline (279.330 us; speedup 1.0000x reference)
//
#include <hip/hip_runtime.h>
#include <stdint.h>

// B=16, N=1024, D=768 fixed for this problem.
#define BB 16
#define NN 1024
#define DD 768

typedef unsigned short u16;
using bf16x8 = __attribute__((ext_vector_type(8))) __bf16;
using f32x4  = __attribute__((ext_vector_type(4))) float;
using u16x8  = __attribute__((ext_vector_type(8))) unsigned short;

__device__ inline u16 f2bf(float x) {
    uint32_t u = __float_as_uint(x);
    u += 0x7fffu + ((u >> 16) & 1u);   // round-to-nearest-even
    return (u16)(u >> 16);
}

__device__ inline void gl_lds16(const void* g, void* l) {
    __builtin_amdgcn_global_load_lds(
        (__attribute__((address_space(1))) void*)g,
        (__attribute__((address_space(3))) void*)l,
        16, 0, 0);
}

__device__ inline void barrier_raw() {
    asm volatile("s_barrier" ::: "memory");
}

// ---------------------------------------------------------------------------
// K1: fp32 [B][N][D] -> bf16 [B][N][D] and bf16 transposed [B][D][N]
// 64x64 tile, vectorized: float4 loads, 16B stores on both outputs.
// grid (D/64, N/64, B), block 256
// ---------------------------------------------------------------------------
__global__ __launch_bounds__(256) void cast_transpose(
    const float* __restrict__ in, u16* __restrict__ outb, u16* __restrict__ outT)
{
    __shared__ u16 tl[64][72];   // [d][n], row = 144 B (16-aligned)
    const int b  = blockIdx.z;
    const int n0 = blockIdx.y * 64;
    const int d0 = blockIdx.x * 64;
    const int t  = threadIdx.x;

    {
        const int r  = t >> 2;        // n-row 0..63
        const int cg = t & 3;         // 16-wide d group
        const float* src = in + ((size_t)b * NN + n0 + r) * DD + d0 + cg * 16;
        u16 h[16];
#pragma unroll
        for (int j = 0; j < 4; ++j) {
            float4 v = *(const float4*)(src + j * 4);
            h[j * 4 + 0] = f2bf(v.x);
            h[j * 4 + 1] = f2bf(v.y);
            h[j * 4 + 2] = f2bf(v.z);
            h[j * 4 + 3] = f2bf(v.w);
        }
        u16* dst = outb + ((size_t)b * NN + n0 + r) * DD + d0 + cg * 16;
        u16x8 p0, p1;
#pragma unroll
        for (int j = 0; j < 8; ++j) { p0[j] = h[j]; p1[j] = h[j + 8]; }
        *(u16x8*)(dst)     = p0;
        *(u16x8*)(dst + 8) = p1;
#pragma unroll
        for (int j = 0; j < 16; ++j) tl[cg * 16 + j][r] = h[j];
    }
    __syncthreads();
    {
        const int d  = t >> 2;        // 0..63
        const int ng = t & 3;         // 16-wide n group
        u16x8 a0 = *(const u16x8*)&tl[d][ng * 16];
        u16x8 a1 = *(const u16x8*)&tl[d][ng * 16 + 8];
        u16* dst = outT + ((size_t)b * DD + d0 + d) * NN + n0 + ng * 16;
        *(u16x8*)(dst)     = a0;
        *(u16x8*)(dst + 8) = a1;
    }
}

// ---------------------------------------------------------------------------
// K2: C[b][i][j] = sum_k A[b][i][k] * B[b][j][k]   (both row-major, K contig)
// Tile 256 x (NFRAG*64), BK=64, 8 waves (2Mx4N), 16x16x32 MFMA.
// 8-phase schedule (4 phases per K-tile, 2 K-tiles per buffer cycle):
//   ph1: ds_read a[m0-3]kk0 + b[all]kk0 | stage A(t+1).half0 -> buf^1
//   ph2: ds_read a[m4-7]kk0 + b[all]kk1 | stage A(t+1).half1
//   ph3: ds_read a[m0-3]kk1
//   ph4: ds_read a[m4-7]kk1 | stage B(t+2) -> same buf | vmcnt(NFRAG) counted
// Each phase: ... -> s_barrier -> setprio(1) MFMA x16 setprio(0) -> s_barrier.
// Counted vmcnt only once per K-tile (never 0 in steady state): B(t+2)'s
// NFRAG loads stay in flight across the tile boundary (T3+T4). Region
// safety: every stage targets LDS freed >=1 barrier-pair earlier.
// XOR-swizzled LDS (linear dest + pre-swizzled global src + swizzled read).
// XCD-aware bijective block swizzle, batch decoded slowest.
// grid (Ncols/(NFRAG*64), M/256, batch), block 512
// ---------------------------------------------------------------------------
template<int NFRAG>
__global__ __launch_bounds__(512) void gemm_bt(
    const u16* __restrict__ A, const u16* __restrict__ B, float* __restrict__ C,
    const int K, const int ldc, const size_t sA, const size_t sB, const size_t sC)
{
    __shared__ u16 lsA[2][256 * 64];
    __shared__ u16 lsB[2][NFRAG * 64 * 64];

    // --- XCD swizzle: dispatch-order id -> owned tile id ---
    const int gx = gridDim.x, gy = gridDim.y;
    const int nwg = gx * gy * gridDim.z;
    int bid = blockIdx.x + gx * (blockIdx.y + gy * blockIdx.z);
    bid = (bid & 7) * (nwg >> 3) + (bid >> 3);
    const int gxy = gx * gy;
    const int bz = bid / gxy;
    const int rem = bid - bz * gxy;
    const int by = rem / gx;
    const int bx = rem - by * gx;

    const int tid = threadIdx.x;
    const int w  = tid >> 6;          // 0..7
    const int l  = tid & 63;
    const int wm = w >> 2;            // 0..1 (row half)
    const int wn = w & 3;             // 0..3 (col quarter)

    const u16* Ab = A + (size_t)bz * sA + (size_t)by * 256 * K;
    const u16* Bb = B + (size_t)bz * sB + (size_t)bx * (NFRAG * 64) * K;

    // staging: thread tid covers row (u*64 + tid>>3), 16B slot (tid&7).
    // LDS dest linear; swizzle realized by pre-swizzling the GLOBAL slot.
    const int trow  = tid >> 3;        // 0..63
    const int gslot = (tid & 7) ^ (trow & 7);
    const u16* Abase = Ab + (size_t)trow * K + gslot * 8;
    const u16* Bbase = Bb + (size_t)trow * K + gslot * 8;
    const int ldsoff = w * 1024;

    auto stageA = [&](int half, int koff, char* dst) {
#pragma unroll
        for (int i = 0; i < 2; ++i) {
            const int j = half * 2 + i;
            gl_lds16(Abase + (size_t)(j * 64) * K + koff, dst + j * 8192 + ldsoff);
        }
    };
    auto stageB = [&](int koff, char* dst) {
#pragma unroll
        for (int u = 0; u < NFRAG; ++u)
            gl_lds16(Bbase + (size_t)(u * 64) * K + koff, dst + u * 8192 + ldsoff);
    };

    // read-side fragment addressing: byte addr (kk=0); kk=1 is addr^64.
    const int lg = l >> 4;   // 0..3
    const int lr = l & 15;
    int adA[8], adB[NFRAG];
#pragma unroll
    for (int m = 0; m < 8; ++m) {
        const int rA = wm * 128 + m * 16 + lr;
        adA[m] = rA * 128 + ((lg ^ (rA & 7)) << 4);
    }
#pragma unroll
    for (int n = 0; n < NFRAG; ++n) {
        const int rB = wn * (NFRAG * 16) + n * 16 + lr;
        adB[n] = rB * 128 + ((lg ^ (rB & 7)) << 4);
    }

    f32x4 acc[8][NFRAG];
#pragma unroll
    for (int i = 0; i < 8; ++i)
#pragma unroll
        for (int j = 0; j < NFRAG; ++j) acc[i][j] = (f32x4){0.f, 0.f, 0.f, 0.f};

    auto wait_counted = []() {
        if constexpr (NFRAG == 4)
            asm volatile("s_waitcnt vmcnt(4)" ::: "memory");
        else
            asm volatile("s_waitcnt vmcnt(3)" ::: "memory");
    };

    const int T = K >> 6;   // 12 (K=768) or 16 (K=1024)

    // prologue: A(0), B(0) -> buf0; B(1) -> buf1; keep B(1) in flight
    stageA(0, 0, (char*)lsA[0]);
    stageA(1, 0, (char*)lsA[0]);
    stageB(0,  (char*)lsB[0]);
    stageB(64, (char*)lsB[1]);
    wait_counted();
    barrier_raw();

    bf16x8 a[4], b0[NFRAG], b1[NFRAG];

    for (int t = 0; t < T; ++t) {
        const int buf = t & 1;
        const char* lA = (const char*)lsA[buf];
        const char* lB = (const char*)lsB[buf];
        char* nA = (char*)lsA[buf ^ 1];
        char* nB = (char*)lsB[buf];
        const bool stA = (t + 1) < T;
        const bool stB = (t + 2) < T;
        const int kA = (t + 1) << 6;
        const int kB = (t + 2) << 6;

        // ---- ph1: m0-3 x kk0
#pragma unroll
        for (int m = 0; m < 4; ++m) a[m] = *(const bf16x8*)(lA + adA[m]);
#pragma unroll
        for (int n = 0; n < NFRAG; ++n) b0[n] = *(const bf16x8*)(lB + adB[n]);
        if (stA) stageA(0, kA, nA);
        barrier_raw();
        __builtin_amdgcn_s_setprio(1);
#pragma unroll
        for (int m = 0; m < 4; ++m)
#pragma unroll
            for (int n = 0; n < NFRAG; ++n)
                acc[m][n] = __builtin_amdgcn_mfma_f32_16x16x32_bf16(
                    a[m], b0[n], acc[m][n], 0, 0, 0);
        __builtin_amdgcn_s_setprio(0);
        barrier_raw();

        // ---- ph2: m4-7 x kk0 (reads b kk1 for later)
#pragma unroll
        for (int m = 0; m < 4; ++m) a[m] = *(const bf16x8*)(lA + adA[4 + m]);
#pragma unroll
        for (int n = 0; n < NFRAG; ++n) b1[n] = *(const bf16x8*)(lB + (adB[n] ^ 64));
        if (stA) stageA(1, kA, nA);
        barrier_raw();
        __builtin_amdgcn_s_setprio(1);
#pragma unroll
        for (int m = 0; m < 4; ++m)
#pragma unroll
            for (int n = 0; n < NFRAG; ++n)
                acc[4 + m][n] = __builtin_amdgcn_mfma_f32_16x16x32_bf16(
                    a[m], b0[n], acc[4 + m][n], 0, 0, 0);
        __builtin_amdgcn_s_setprio(0);
        barrier_raw();

        // ---- ph3: m0-3 x kk1
#pragma unroll
        for (int m = 0; m < 4; ++m) a[m] = *(const bf16x8*)(lA + (adA[m] ^ 64));
        barrier_raw();
        __builtin_amdgcn_s_setprio(1);
#pragma unroll
        for (int m = 0; m < 4; ++m)
#pragma unroll
            for (int n = 0; n < NFRAG; ++n)
                acc[m][n] = __builtin_amdgcn_mfma_f32_16x16x32_bf16(
                    a[m], b1[n], acc[m][n], 0, 0, 0);
        __builtin_amdgcn_s_setprio(0);
        barrier_raw();

        // ---- ph4: m4-7 x kk1; stage B(t+2); counted vmcnt once per K-tile
#pragma unroll
        for (int m = 0; m < 4; ++m) a[m] = *(const bf16x8*)(lA + (adA[4 + m] ^ 64));
        if (stB) {
            stageB(kB, nB);
            wait_counted();
        } else if (stA) {
            asm volatile("s_waitcnt vmcnt(0)" ::: "memory");
        }
        barrier_raw();
        __builtin_amdgcn_s_setprio(1);
#pragma unroll
        for (int m = 0; m < 4; ++m)
#pragma unroll
            for (int n = 0; n < NFRAG; ++n)
                acc[4 + m][n] = __builtin_amdgcn_mfma_f32_16x16x32_bf16(
                    a[m], b1[n], acc[4 + m][n], 0, 0, 0);
        __builtin_amdgcn_s_setprio(0);
        barrier_raw();
    }

    float* Cb = C + (size_t)bz * sC;
    const int crow = by * 256 + wm * 128 + lg * 4;
    const int ccol = bx * (NFRAG * 64) + wn * (NFRAG * 16) + lr;
#pragma unroll
    for (int m = 0; m < 8; ++m)
#pragma unroll
        for (int n = 0; n < NFRAG; ++n)
#pragma unroll
            for (int r = 0; r < 4; ++r)
                Cb[(size_t)(crow + m * 16 + r) * ldc + ccol + n * 16] = acc[m][n][r];
}

// ---------------------------------------------------------------------------
// K3: row softmax over 1024 fp32 -> bf16, vectorized. grid = rows, block 256
// ---------------------------------------------------------------------------
__global__ __launch_bounds__(256) void softmax_rows(
    const float* __restrict__ sim, u16* __restrict__ attn)
{
    __shared__ float red[4];
    const size_t row = blockIdx.x;
    const int t = threadIdx.x;

    float4 v = *(const float4*)(sim + row * NN + t * 4);
    float m = fmaxf(fmaxf(v.x, v.y), fmaxf(v.z, v.w));
#pragma unroll
    for (int o = 32; o > 0; o >>= 1) m = fmaxf(m, __shfl_xor(m, o, 64));
    if ((t & 63) == 0) red[t >> 6] = m;
    __syncthreads();
    m = fmaxf(fmaxf(red[0], red[1]), fmaxf(red[2], red[3]));
    __syncthreads();

    float e0 = __expf(v.x - m), e1 = __expf(v.y - m);
    float e2 = __expf(v.z - m), e3 = __expf(v.w - m);
    float s = e0 + e1 + e2 + e3;
#pragma unroll
    for (int o = 32; o > 0; o >>= 1) s += __shfl_xor(s, o, 64);
    if ((t & 63) == 0) red[t >> 6] = s;
    __syncthreads();
    s = red[0] + red[1] + red[2] + red[3];
    const float inv = 1.0f / s;

    ushort4 o4;
    o4.x = f2bf(e0 * inv); o4.y = f2bf(e1 * inv);
    o4.z = f2bf(e2 * inv); o4.w = f2bf(e3 * inv);
    *(ushort4*)(attn + row * NN + t * 4) = o4;
}

// ---------------------------------------------------------------------------
// K4: in-place io = io/max(||io||,eps) + 2*img, per row of 768, vectorized.
// grid = B*N, block 192 (192*4 = 768)
// ---------------------------------------------------------------------------
__global__ __launch_bounds__(192) void norm_add(
    float* __restrict__ io, const float* __restrict__ img)
{
    __shared__ float red[3];
    const size_t row = blockIdx.x;
    float* p = io + row * DD;
    const float* q = img + row * DD;
    const int t = threadIdx.x;

    float4 x = *(const float4*)(p + t * 4);
    float s = x.x * x.x + x.y * x.y + x.z * x.z + x.w * x.w;
#pragma unroll
    for (int o = 32; o > 0; o >>= 1) s += __shfl_xor(s, o, 64);
    if ((t & 63) == 0) red[t >> 6] = s;
    __syncthreads();
    s = red[0] + red[1] + red[2];
    const float sc = 1.0f / fmaxf(sqrtf(s), 1e-12f);

    float4 g = *(const float4*)(q + t * 4);
    float4 o4;
    o4.x = x.x * sc + 2.0f * g.x;
    o4.y = x.y * sc + 2.0f * g.y;
    o4.z = x.z * sc + 2.0f * g.z;
    o4.w = x.w * sc + 2.0f * g.w;
    *(float4*)(p + t * 4) = o4;
}

// ---------------------------------------------------------------------------
extern "C" void kernel_launch(void* const* d_in, const int* in_sizes, int n_in,
                              void* d_out, int out_size, void* d_ws, size_t ws_size,
                              hipStream_t stream)
{
    const float* img1 = (const float*)d_in[0];
    const float* img2 = (const float*)d_in[1];
    float* out = (float*)d_out;

    const size_t NBD = (size_t)BB * NN * DD;       // 12582912 elems
    u16* i1b = (u16*)d_ws;
    u16* i2b = i1b + NBD;
    u16* i1t = i2b + NBD;
    u16* i2t = i1t + NBD;
    char* rest = (char*)(i2t + NBD);
    const size_t baseBytes = 4 * NBD * sizeof(u16);

    int CB = 16;
    while (CB > 1 && baseBytes + (size_t)CB * NN * NN * 6 > ws_size) CB >>= 1;

    float* sim = (float*)rest;
    u16* attn = (u16*)(rest + (size_t)CB * NN * NN * 4);

    const size_t sND = (size_t)NN * DD;   // 786432
    const size_t sNNe = (size_t)NN * NN;  // 1048576

    cast_transpose<<<dim3(DD / 64, NN / 64, BB), 256, 0, stream>>>(img1, i1b, i1t);
    cast_transpose<<<dim3(DD / 64, NN / 64, BB), 256, 0, stream>>>(img2, i2b, i2t);

    // Direction A: Q=img1, K/V=img2 -> output slot 1 (out2)
    for (int b0 = 0; b0 < BB; b0 += CB) {
        gemm_bt<4><<<dim3(NN / 256, NN / 256, CB), 512, 0, stream>>>(
            i1b + (size_t)b0 * sND, i2b + (size_t)b0 * sND, sim,
            DD, NN, sND, sND, sNNe);
        softmax_rows<<<dim3(CB * NN), 256, 0, stream>>>(sim, attn);
        gemm_bt<3><<<dim3(DD / 192, NN / 256, CB), 512, 0, stream>>>(
            attn, i2t + (size_t)b0 * sND, out + NBD + (size_t)b0 * sND,
            NN, DD, sNNe, sND, sND);
    }
    norm_add<<<dim3(BB * NN), 192, 0, stream>>>(out + NBD, img2);

    // Direction B: Q=img2, K/V=img1 -> output slot 0 (out1)
    for (int b0 = 0; b0 < BB; b0 += CB) {
        gemm_bt<4><<<dim3(NN / 256, NN / 256, CB), 512, 0, stream>>>(
            i2b + (size_t)b0 * sND, i1b + (size_t)b0 * sND, sim,
            DD, NN, sND, sND, sNNe);
        softmax_rows<<<dim3(CB * NN), 256, 0, stream>>>(sim, attn);
        gemm_bt<3><<<dim3(DD / 192, NN / 256, CB), 512, 0, stream>>>(
            attn, i1t + (size_t)b0 * sND, out + (size_t)b0 * sND,
            NN, DD, sNNe, sND, sND);
    }
    norm_add<<<dim3(BB * NN), 192, 0, stream>>>(out, img1);
}

// Round 6
// 275.536 us; speedup vs baseline: 1.0138x; 1.0138x over previous
//
#include <hip/hip_runtime.h>
#include <stdint.h>

// B=16, N=1024, D=768 fixed for this problem.
#define BB 16
#define NN 1024
#define DD 768

typedef unsigned short u16;
using bf16x8 = __attribute__((ext_vector_type(8))) __bf16;
using f32x4  = __attribute__((ext_vector_type(4))) float;
using u16x8  = __attribute__((ext_vector_type(8))) unsigned short;

__device__ inline u16 f2bf(float x) {
    uint32_t u = __float_as_uint(x);
    u += 0x7fffu + ((u >> 16) & 1u);   // round-to-nearest-even
    return (u16)(u >> 16);
}

// ---------------------------------------------------------------------------
// K1: fp32 [B][N][D] -> bf16 [B][N][D] and bf16 transposed [B][D][N]
// 64x64 tile, vectorized: float4 loads, 16B stores on both outputs.
// grid (D/64, N/64, B), block 256
// ---------------------------------------------------------------------------
__global__ __launch_bounds__(256) void cast_transpose(
    const float* __restrict__ in, u16* __restrict__ outb, u16* __restrict__ outT)
{
    __shared__ u16 tl[64][72];   // [d][n], row = 144 B (16-aligned)
    const int b  = blockIdx.z;
    const int n0 = blockIdx.y * 64;
    const int d0 = blockIdx.x * 64;
    const int t  = threadIdx.x;

    {
        const int r  = t >> 2;        // n-row 0..63
        const int cg = t & 3;         // 16-wide d group
        const float* src = in + ((size_t)b * NN + n0 + r) * DD + d0 + cg * 16;
        u16 h[16];
#pragma unroll
        for (int j = 0; j < 4; ++j) {
            float4 v = *(const float4*)(src + j * 4);
            h[j * 4 + 0] = f2bf(v.x);
            h[j * 4 + 1] = f2bf(v.y);
            h[j * 4 + 2] = f2bf(v.z);
            h[j * 4 + 3] = f2bf(v.w);
        }
        u16* dst = outb + ((size_t)b * NN + n0 + r) * DD + d0 + cg * 16;
        u16x8 p0, p1;
#pragma unroll
        for (int j = 0; j < 8; ++j) { p0[j] = h[j]; p1[j] = h[j + 8]; }
        *(u16x8*)(dst)     = p0;
        *(u16x8*)(dst + 8) = p1;
#pragma unroll
        for (int j = 0; j < 16; ++j) tl[cg * 16 + j][r] = h[j];
    }
    __syncthreads();
    {
        const int d  = t >> 2;        // 0..63
        const int ng = t & 3;         // 16-wide n group
        u16x8 a0 = *(const u16x8*)&tl[d][ng * 16];
        u16x8 a1 = *(const u16x8*)&tl[d][ng * 16 + 8];
        u16* dst = outT + ((size_t)b * DD + d0 + d) * NN + n0 + ng * 16;
        *(u16x8*)(dst)     = a0;
        *(u16x8*)(dst + 8) = a1;
    }
}

// ---------------------------------------------------------------------------
// K2: fully fused cross-attention direction:
//   out[q][:] = l2norm( softmax_q( Q[q]·K^T ) @ V ) + 2*G[q][:]
// One block = 64 q-rows of one batch. 8 waves, 512 threads, 1 block/CU.
//
// Phase 1 (S^T = K @ Q^T): wave w owns keys [w*128,+128). K streams
//   global->reg (waves disjoint => no LDS, no barriers in k-loop);
//   Q-tile (64x768 bf16, 96KB) in XOR-swizzled LDS.
//   C-frag: key = m*16+lg*4+reg, q = n*16+lr.
// Phase 2: row-max over keys (shfl over lg + 2KB LDS cross-wave).
//   Softmax SUM IS SKIPPED: l2norm(O/s) == l2norm(O) (scale-invariant).
// Phase 3: P = exp(S-max) -> bf16 LDS [64 q][1024 keys] (reuses Q region,
//   128KB), packed 4 keys/lane-reg -> ds_write_b64, same XOR swizzle.
// Phase 4 (O^T = V^T @ P): wave w owns d-rows [w*96,+96). V^T streams
//   global->reg, P read from LDS. Block holds ALL 768 d per q.
// Phase 5: l2-norm per q (shfl + 2KB LDS) + out = O*inv + 2*G, float4.
// Barriers per block: 4 total.
// grid (256) = 16 qtiles x 16 batches, XCD-pinned: batch = (bid&7)*2+((bid>>3)&1)
// ---------------------------------------------------------------------------
__global__ __launch_bounds__(512, 1) void fused_attn(
    const u16* __restrict__ Qb,   // [B][N][D] bf16  (query-side image)
    const u16* __restrict__ Kb,   // [B][N][D] bf16  (kv-side image)
    const u16* __restrict__ Vt,   // [B][D][N] bf16  (kv-side transposed)
    const float* __restrict__ Gf, // [B][N][D] fp32  (kv-side image)
    float* __restrict__ Out)      // [B][N][D] fp32
{
    __shared__ char PQ[131072];      // Q tile (96KB) then P (128KB)
    __shared__ float RED[8][64];     // cross-wave reduction scratch

    const int bid = blockIdx.x;
    const int j   = bid >> 3;
    const int b   = (bid & 7) * 2 + (j & 1);   // XCD x owns batches 2x,2x+1
    const int q0  = (j >> 1) * 64;

    const int tid = threadIdx.x;
    const int w  = tid >> 6;          // 0..7
    const int l  = tid & 63;
    const int lr = l & 15;
    const int lg = l >> 4;

    const u16* qp = Qb + ((size_t)b * NN + q0) * DD;
    const u16* kp = Kb + (size_t)b * NN * DD;
    const u16* vp = Vt + (size_t)b * DD * NN;

    // ---- stage Q tile 64x768 into LDS (16B slots, slot ^= q&7)
#pragma unroll
    for (int i = 0; i < 12; ++i) {
        const int S = i * 512 + tid;          // 0..6143
        const int q = S / 96, sl = S % 96;
        bf16x8 v = *(const bf16x8*)(qp + (size_t)q * DD + sl * 8);
        *(bf16x8*)(PQ + q * 1536 + ((sl ^ (q & 7)) << 4)) = v;
    }
    __syncthreads();

    // ---- Phase 1: S^T = K @ Q^T (keys x q), barrier-free k-loop
    f32x4 accS[8][4];
#pragma unroll
    for (int m = 0; m < 8; ++m)
#pragma unroll
        for (int n = 0; n < 4; ++n) accS[m][n] = (f32x4){0.f, 0.f, 0.f, 0.f};

    for (int kt = 0; kt < DD / 64; ++kt) {
#pragma unroll
        for (int kk = 0; kk < 2; ++kk) {
            const int kc = kt * 64 + kk * 32 + lg * 8;
            bf16x8 a[8], bq[4];
#pragma unroll
            for (int m = 0; m < 8; ++m)
                a[m] = *(const bf16x8*)(kp + (size_t)(w * 128 + m * 16 + lr) * DD + kc);
            const int sl = kt * 8 + kk * 4 + lg;
#pragma unroll
            for (int n = 0; n < 4; ++n) {
                const int q = n * 16 + lr;
                bq[n] = *(const bf16x8*)(PQ + q * 1536 + ((sl ^ (q & 7)) << 4));
            }
#pragma unroll
            for (int m = 0; m < 8; ++m)
#pragma unroll
                for (int n = 0; n < 4; ++n)
                    accS[m][n] = __builtin_amdgcn_mfma_f32_16x16x32_bf16(
                        a[m], bq[n], accS[m][n], 0, 0, 0);
        }
    }

    // ---- Phase 2: row max over all 1024 keys, per q
    float mx[4];
#pragma unroll
    for (int n = 0; n < 4; ++n) {
        float v = -3.4e38f;
#pragma unroll
        for (int m = 0; m < 8; ++m)
#pragma unroll
            for (int r = 0; r < 4; ++r) v = fmaxf(v, accS[m][n][r]);
        v = fmaxf(v, __shfl_xor(v, 16, 64));
        v = fmaxf(v, __shfl_xor(v, 32, 64));
        mx[n] = v;
    }
    if (l < 16) {
#pragma unroll
        for (int n = 0; n < 4; ++n) RED[w][n * 16 + l] = mx[n];
    }
    __syncthreads();
    float rmax[4];
#pragma unroll
    for (int n = 0; n < 4; ++n) {
        const int q = n * 16 + lr;
        float v = RED[0][q];
#pragma unroll
        for (int ww = 1; ww < 8; ++ww) v = fmaxf(v, RED[ww][q]);
        rmax[n] = v;
    }

    // ---- Phase 3: P = exp(S - rowmax) -> bf16 LDS [64 q][1024 keys]
#pragma unroll
    for (int m = 0; m < 8; ++m)
#pragma unroll
        for (int n = 0; n < 4; ++n) {
            ushort4 pk;
            pk.x = f2bf(__expf(accS[m][n][0] - rmax[n]));
            pk.y = f2bf(__expf(accS[m][n][1] - rmax[n]));
            pk.z = f2bf(__expf(accS[m][n][2] - rmax[n]));
            pk.w = f2bf(__expf(accS[m][n][3] - rmax[n]));
            const int q    = n * 16 + lr;
            const int key  = w * 128 + m * 16 + lg * 4;
            const int slot = key >> 3;
            *(ushort4*)(PQ + q * 2048 + ((slot ^ (q & 7)) << 4) + (key & 7) * 2) = pk;
        }
    __syncthreads();

    // ---- Phase 4: O^T = V^T @ P (d x q), barrier-free k-loop
    f32x4 accO[6][4];
#pragma unroll
    for (int m = 0; m < 6; ++m)
#pragma unroll
        for (int n = 0; n < 4; ++n) accO[m][n] = (f32x4){0.f, 0.f, 0.f, 0.f};

    for (int kt = 0; kt < NN / 64; ++kt) {
#pragma unroll
        for (int kk = 0; kk < 2; ++kk) {
            const int kc = kt * 64 + kk * 32 + lg * 8;
            bf16x8 a[6], bp[4];
#pragma unroll
            for (int m = 0; m < 6; ++m)
                a[m] = *(const bf16x8*)(vp + (size_t)(w * 96 + m * 16 + lr) * NN + kc);
            const int sl = kt * 8 + kk * 4 + lg;
#pragma unroll
            for (int n = 0; n < 4; ++n) {
                const int q = n * 16 + lr;
                bp[n] = *(const bf16x8*)(PQ + q * 2048 + ((sl ^ (q & 7)) << 4));
            }
#pragma unroll
            for (int m = 0; m < 6; ++m)
#pragma unroll
                for (int n = 0; n < 4; ++n)
                    accO[m][n] = __builtin_amdgcn_mfma_f32_16x16x32_bf16(
                        a[m], bp[n], accO[m][n], 0, 0, 0);
        }
    }

    // ---- Phase 5: l2 norm per q over d (sum of squares), then write out
    float s2[4];
#pragma unroll
    for (int n = 0; n < 4; ++n) {
        float v = 0.f;
#pragma unroll
        for (int m = 0; m < 6; ++m)
#pragma unroll
            for (int r = 0; r < 4; ++r) v += accO[m][n][r] * accO[m][n][r];
        v += __shfl_xor(v, 16, 64);
        v += __shfl_xor(v, 32, 64);
        s2[n] = v;
    }
    if (l < 16) {
#pragma unroll
        for (int n = 0; n < 4; ++n) RED[w][n * 16 + l] = s2[n];
    }
    __syncthreads();
    float inv[4];
#pragma unroll
    for (int n = 0; n < 4; ++n) {
        const int q = n * 16 + lr;
        float v = RED[0][q];
#pragma unroll
        for (int ww = 1; ww < 8; ++ww) v += RED[ww][q];
        inv[n] = 1.f / fmaxf(sqrtf(v), 1e-12f);
    }

    float* op = Out + ((size_t)b * NN + q0) * DD;
    const float* gp = Gf + ((size_t)b * NN + q0) * DD;
#pragma unroll
    for (int m = 0; m < 6; ++m)
#pragma unroll
        for (int n = 0; n < 4; ++n) {
            const int q  = n * 16 + lr;
            const int d0 = w * 96 + m * 16 + lg * 4;
            const size_t off = (size_t)q * DD + d0;
            float4 g = *(const float4*)(gp + off);
            float4 o;
            o.x = accO[m][n][0] * inv[n] + 2.f * g.x;
            o.y = accO[m][n][1] * inv[n] + 2.f * g.y;
            o.z = accO[m][n][2] * inv[n] + 2.f * g.z;
            o.w = accO[m][n][3] * inv[n] + 2.f * g.w;
            *(float4*)(op + off) = o;
        }
}

// ---------------------------------------------------------------------------
extern "C" void kernel_launch(void* const* d_in, const int* in_sizes, int n_in,
                              void* d_out, int out_size, void* d_ws, size_t ws_size,
                              hipStream_t stream)
{
    const float* img1 = (const float*)d_in[0];
    const float* img2 = (const float*)d_in[1];
    float* out = (float*)d_out;

    const size_t NBD = (size_t)BB * NN * DD;       // 12582912 elems
    u16* i1b = (u16*)d_ws;
    u16* i2b = i1b + NBD;
    u16* i1t = i2b + NBD;
    u16* i2t = i1t + NBD;

    cast_transpose<<<dim3(DD / 64, NN / 64, BB), 256, 0, stream>>>(img1, i1b, i1t);
    cast_transpose<<<dim3(DD / 64, NN / 64, BB), 256, 0, stream>>>(img2, i2b, i2t);

    // Direction A: Q=img1, K/V=img2 -> out2 (slot 1)
    fused_attn<<<dim3(256), 512, 0, stream>>>(i1b, i2b, i2t, img2, out + NBD);
    // Direction B: Q=img2, K/V=img1 -> out1 (slot 0)
    fused_attn<<<dim3(256), 512, 0, stream>>>(i2b, i1b, i1t, img1, out);
}